// Round 19
// baseline (123.386 us; speedup 1.0000x reference)
//
#include <hip/hip_runtime.h>
#include <hip/hip_bf16.h>

typedef __bf16 bf16;
typedef __bf16 bf16x4 __attribute__((ext_vector_type(4)));
typedef __bf16 bf16x8 __attribute__((ext_vector_type(8)));
typedef float  f32x4  __attribute__((ext_vector_type(4)));

// Problem constants: B=16, T=1024, C=512, H=8, Dh=64
#define BB 16
#define TT 1024
#define CC 512
#define HH 8
#define DH 64

// 0.125 (1/sqrt(Dh)) * log2(e): folded into Q so softmax uses exp2 directly.
#define QSCALE 0.18033688011112042f
#define RESCALE_THR 10.0f

__device__ __forceinline__ void gload16(const void* gsrc, void* ldst) {
    __builtin_amdgcn_global_load_lds(
        (const __attribute__((address_space(1))) void*)gsrc,
        (__attribute__((address_space(3))) void*)ldst, 16, 0, 0);
}

__device__ __forceinline__ f32x4 mfma16(bf16x8 a, bf16x8 b, f32x4 c) {
    return __builtin_amdgcn_mfma_f32_16x16x32_bf16(a, b, c, 0, 0, 0);
}

// ---------------- fused prep: x->bf16, Wqkv^T, Wout^T in one launch ----------------
__global__ __launch_bounds__(256)
void k_prep(const float* __restrict__ x, const float* __restrict__ wqkv,
            const float* __restrict__ wout,
            bf16* __restrict__ xb, bf16* __restrict__ wqt, bf16* __restrict__ wot)
{
    const int stride = gridDim.x * blockDim.x;
    const int i0 = blockIdx.x * blockDim.x + threadIdx.x;
    const int NX4 = BB * TT * CC / 4;
    for (int i = i0; i < NX4; i += stride) {
        float4 v = *(const float4*)(x + (size_t)i * 4);
        bf16x4 o = { (bf16)v.x, (bf16)v.y, (bf16)v.z, (bf16)v.w };
        *(bf16x4*)(xb + (size_t)i * 4) = o;
    }
    const int NQ = CC * 3 * CC;
    for (int i = i0; i < NQ; i += stride) {
        int k = i / (3 * CC), n = i - k * (3 * CC);
        wqt[(size_t)n * CC + k] = (bf16)wqkv[i];
    }
    const int NO = CC * CC;
    for (int i = i0; i < NO; i += stride) {
        int k = i / CC, n = i - k * CC;
        wot[(size_t)n * CC + k] = (bf16)wout[i];
    }
}

// ---------------- GEMM: C[M,N] = A[M,K] * Bt[N,K]^T ----------------
// (byte-identical to R17/R18) Swapped MFMA operands -> rg spans 4 consecutive
// columns -> vectorized epilogue (f32x4 / bf16x4 stores). BK=64, linear
// global_load_lds staging, XCD-aware swizzle.
template<int MODE>
__global__ __launch_bounds__(256)
void k_gemm_bt(const bf16* __restrict__ A, const bf16* __restrict__ Bt,
               int M, int N, int K,
               float* __restrict__ outF,
               bf16* __restrict__ qb, bf16* __restrict__ kb, bf16* __restrict__ vtb)
{
    __shared__ bf16 sA[2 * 128 * 32];   // [kk][row][32]
    __shared__ bf16 sB[2 * 128 * 32];
    const int tid  = threadIdx.x;
    const int wid  = tid >> 6;
    const int lane = tid & 63;
    const int l15  = lane & 15, l4 = lane >> 4;

    const int cpx = gridDim.x >> 3;
    const int bid = (blockIdx.x & 7) * cpx + (blockIdx.x >> 3);

    const int nNt = N >> 7;
    const int mt  = bid / nNt;
    const int nt  = bid - mt * nNt;
    const int m0  = mt << 7, n0 = nt << 7;
    const int wr  = (wid >> 1) * 64, wc = (wid & 1) * 64;

    f32x4 zero = {0.f, 0.f, 0.f, 0.f};
    f32x4 acc[4][4];
#pragma unroll
    for (int i = 0; i < 4; ++i)
#pragma unroll
        for (int j = 0; j < 4; ++j) acc[i][j] = zero;

    int srow[4], scol[4], soff[4];
#pragma unroll
    for (int c = 0; c < 4; ++c) {
        const int cc = wid * 4 + c;                  // 0..15
        srow[c] = (cc & 7) * 16 + (lane >> 2);       // tile row 0..127
        scol[c] = (cc >> 3) * 32 + (lane & 3) * 8;   // k offset within 64
        soff[c] = cc * 512;                          // LDS elem base (wave-uniform)
    }

    for (int k0 = 0; k0 < K; k0 += 64) {
#pragma unroll
        for (int c = 0; c < 4; ++c)
            gload16(A  + (size_t)(m0 + srow[c]) * K + k0 + scol[c], sA + soff[c]);
#pragma unroll
        for (int c = 0; c < 4; ++c)
            gload16(Bt + (size_t)(n0 + srow[c]) * K + k0 + scol[c], sB + soff[c]);
        __syncthreads();
        bf16x8 af[4][2], bfr[4][2];
#pragma unroll
        for (int kk = 0; kk < 2; ++kk) {
#pragma unroll
            for (int i = 0; i < 4; ++i)
                af[i][kk] = *(const bf16x8*)(sA + kk * 4096 + (wr + i * 16 + l15) * 32 + l4 * 8);
#pragma unroll
            for (int j = 0; j < 4; ++j)
                bfr[j][kk] = *(const bf16x8*)(sB + kk * 4096 + (wc + j * 16 + l15) * 32 + l4 * 8);
        }
#pragma unroll
        for (int kk = 0; kk < 2; ++kk)
#pragma unroll
            for (int i = 0; i < 4; ++i)
#pragma unroll
                for (int j = 0; j < 4; ++j)
                    acc[i][j] = mfma16(bfr[j][kk], af[i][kk], acc[i][j]);   // swapped
        __syncthreads();
    }

    // vectorized epilogue: rm per (i); cn0..cn0+3 contiguous per (i,j)
#pragma unroll
    for (int i = 0; i < 4; ++i) {
        const int rm = m0 + wr + i * 16 + l15;
#pragma unroll
        for (int j = 0; j < 4; ++j) {
            const int cn0 = n0 + wc + j * 16 + l4 * 4;
            if (MODE == 0) {
                *(f32x4*)(&outF[(size_t)rm * N + cn0]) = acc[i][j];
            } else {
                int b = rm >> 10, t = rm & 1023;
                int s = cn0 >> 9, h = (cn0 >> 6) & 7, d0 = cn0 & 63;
                size_t bh = (size_t)(b * HH + h);
                if (s == 0) {
                    bf16x4 o = { (bf16)(acc[i][j][0] * QSCALE), (bf16)(acc[i][j][1] * QSCALE),
                                 (bf16)(acc[i][j][2] * QSCALE), (bf16)(acc[i][j][3] * QSCALE) };
                    *(bf16x4*)(qb + (bh * TT + t) * DH + d0) = o;
                } else if (s == 1) {
                    bf16x4 o = { (bf16)acc[i][j][0], (bf16)acc[i][j][1],
                                 (bf16)acc[i][j][2], (bf16)acc[i][j][3] };
                    *(bf16x4*)(kb + (bh * TT + t) * DH + d0) = o;
                } else {
#pragma unroll
                    for (int rg = 0; rg < 4; ++rg)
                        vtb[(bh * DH + d0 + rg) * TT + t] = (bf16)acc[i][j][rg];
                }
            }
        }
    }
}

// ---------------- flash attention v9: 8 waves x 16 rows ----------------
// R19 delta vs R18: __builtin_amdgcn_sched_barrier(0) pins the prefetch-issue
// point — the compiler (at 44 VGPR) was sinking the T14 prefetch load to its
// use point, re-exposing global latency every tile. The fence forces early
// issue, making sreg live across compute (VGPR rises, latency hidden).
// Compile-time scheduling constraint only; no runtime/arithmetic change.
__global__ __launch_bounds__(512, 4)
void k_attn(const bf16* __restrict__ qg, const bf16* __restrict__ kg,
            const bf16* __restrict__ vtg, bf16* __restrict__ yb)
{
    __shared__ __align__(16) bf16 sK[2][32 * 72];   // [k-row][dh], row stride 72
    __shared__ __align__(16) bf16 sV[2][64 * 40];   // [d][k],     row stride 40
    __shared__ __align__(16) bf16 sP[8][16 * 40];   // per-wave P tile (16 rows)
    const int tid = threadIdx.x, w = tid >> 6, lane = tid & 63;
    const int l15 = lane & 15, l4 = lane >> 4;

    const int bid = blockIdx.x;          // 0..511
    const int xcd = bid & 7;
    const int j   = bid >> 3;            // 0..63
    const int bh  = xcd * 16 + (j >> 2); // 0..127
    const int qp  = j & 3;               // pair id 0..3

    const bf16* Q  = qg  + (size_t)bh * TT * DH;
    const bf16* Kp = kg  + (size_t)bh * TT * DH;
    const bf16* Vt = vtg + (size_t)bh * DH * TT;
    const int b = bh >> 3, h = bh & 7;

    const bool kstage = (tid < 256);
    const int ks_row = tid >> 3;                  // 0..31 (valid when kstage)
    const int ks_col = (tid & 7) * 8;             // 0..56
    const int t2 = tid & 255;
    const int vs_row = t2 >> 2;                   // 0..63 (d)
    const int vs_col = (t2 & 3) * 8;              // 0..24

    bf16* myP = &sP[w][0];
    const f32x4 zero = {0.f, 0.f, 0.f, 0.f};

    for (int up = 0; up < 2; ++up) {
        const int qblk = up ? (7 - qp) : qp;   // q-block 0..7 (128 rows)
        const int qb   = qblk * 128 + w * 16;  // this wave's 16 q-rows [qb, qb+16)
        const int nt   = (qblk + 1) * 4;       // causal KV tiles of 32

        bf16x8 qf[2];
#pragma unroll
        for (int kk = 0; kk < 2; ++kk)
            qf[kk] = *(const bf16x8*)(Q + (size_t)(qb + l15) * DH + kk * 32 + l4 * 8);

        f32x4 y[4];
        float m_ = -1e30f, lp_ = 0.f;
#pragma unroll
        for (int dj = 0; dj < 4; ++dj) y[dj] = zero;

        if (kstage) {
            uint4 k0 = *(const uint4*)(Kp + (size_t)ks_row * DH + ks_col);
            *(uint4*)(&sK[0][ks_row * 72 + ks_col]) = k0;
        } else {
            uint4 v0 = *(const uint4*)(Vt + (size_t)vs_row * TT + vs_col);
            *(uint4*)(&sV[0][vs_row * 40 + vs_col]) = v0;
        }
        __syncthreads();

        for (int t = 0; t < nt; ++t) {
            const int t0 = t * 32;
            const int cur = t & 1, nxt = cur ^ 1;
            const bool more = (t + 1 < nt);
            uint4 sreg;
            if (more) {   // T14: issue next tile's global load early
                sreg = kstage
                    ? *(const uint4*)(Kp + (size_t)(t0 + 32 + ks_row) * DH + ks_col)
                    : *(const uint4*)(Vt + (size_t)vs_row * TT + t0 + 32 + vs_col);
            }
            __builtin_amdgcn_sched_barrier(0);   // pin prefetch issue before compute

            if (t0 < qb + 16) {   // wave-uniform causal skip
                bf16x8 kf[2][2];
#pragma unroll
                for (int nj = 0; nj < 2; ++nj) {
                    const int row = nj * 16 + l15;
#pragma unroll
                    for (int kk = 0; kk < 2; ++kk)
                        kf[nj][kk] = *(const bf16x8*)(&sK[cur][row * 72 + ((kk << 2) | l4) * 8]);
                }
                f32x4 s[2];
#pragma unroll
                for (int nj = 0; nj < 2; ++nj) {
                    f32x4 a = mfma16(kf[nj][0], qf[0], zero);
                    s[nj] = mfma16(kf[nj][1], qf[1], a);
                }
                if (t0 + 32 > qb) {   // straddling tile: absolute-coord mask
#pragma unroll
                    for (int nj = 0; nj < 2; ++nj)
#pragma unroll
                        for (int rg = 0; rg < 4; ++rg)
                            if (t0 + nj * 16 + l4 * 4 + rg > qb + l15)
                                s[nj][rg] = -1e30f;
                }
                float mx = fmaxf(fmaxf(fmaxf(s[0][0], s[0][1]), fmaxf(s[0][2], s[0][3])),
                                 fmaxf(fmaxf(s[1][0], s[1][1]), fmaxf(s[1][2], s[1][3])));
                mx = fmaxf(mx, __shfl_xor(mx, 16));
                mx = fmaxf(mx, __shfl_xor(mx, 32));
                if (__any(mx > m_ + RESCALE_THR)) {   // T13 defer-rescale
                    float mnew = fmaxf(m_, mx);
                    float corr = exp2f(m_ - mnew);
                    lp_ *= corr;
                    float cr[4];
#pragma unroll
                    for (int rg = 0; rg < 4; ++rg)
                        cr[rg] = __shfl(corr, ((lane >> 4) << 2) | rg);
#pragma unroll
                    for (int dj = 0; dj < 4; ++dj)
#pragma unroll
                        for (int rg = 0; rg < 4; ++rg) y[dj][rg] *= cr[rg];
                    m_ = mnew;
                }
                bf16x4 pk0, pk1;
#pragma unroll
                for (int rg = 0; rg < 4; ++rg) {
                    float p0 = exp2f(s[0][rg] - m_);
                    float p1 = exp2f(s[1][rg] - m_);
                    lp_ += p0 + p1;
                    pk0[rg] = (bf16)p0;
                    pk1[rg] = (bf16)p1;
                }
                *(bf16x4*)(myP + l15 * 40 + l4 * 4)      = pk0;
                *(bf16x4*)(myP + l15 * 40 + 16 + l4 * 4) = pk1;

                bf16x8 pa = *(const bf16x8*)(myP + l15 * 40 + l4 * 8);
                bf16x8 vf[4];
#pragma unroll
                for (int dj = 0; dj < 4; ++dj)
                    vf[dj] = *(const bf16x8*)(&sV[cur][(dj * 16 + l15) * 40 + l4 * 8]);
#pragma unroll
                for (int dj = 0; dj < 4; ++dj)
                    y[dj] = mfma16(pa, vf[dj], y[dj]);
            }

            if (more) {   // T14: write-late into the other buffer (split)
                if (kstage) *(uint4*)(&sK[nxt][ks_row * 72 + ks_col]) = sreg;
                else        *(uint4*)(&sV[nxt][vs_row * 40 + vs_col]) = sreg;
            }
            __syncthreads();
        }

        // epilogue: row denominator, redistribute to y-row layout, store
        lp_ += __shfl_xor(lp_, 16);
        lp_ += __shfl_xor(lp_, 32);
#pragma unroll
        for (int rg = 0; rg < 4; ++rg) {
            float inv = 1.0f / __shfl(lp_, ((lane >> 4) << 2) | rg);
            int rr = qb + l4 * 4 + rg;
#pragma unroll
            for (int dj = 0; dj < 4; ++dj) {
                int cc = h * DH + dj * 16 + l15;
                yb[((size_t)b * TT + rr) * CC + cc] = (bf16)(y[dj][rg] * inv);
            }
        }
        __syncthreads();   // protect sK/sV reuse across up iterations
    }
}

// ---------------- launch ----------------
extern "C" void kernel_launch(void* const* d_in, const int* in_sizes, int n_in,
                              void* d_out, int out_size, void* d_ws, size_t ws_size,
                              hipStream_t stream)
{
    const float* x    = (const float*)d_in[0];   // [16,1024,512]
    const float* wqkv = (const float*)d_in[1];   // [512,1536]
    const float* wout = (const float*)d_in[2];   // [512,512]
    float* out = (float*)d_out;                  // [16,1024,512] fp32

    const size_t NX = (size_t)BB * TT * CC;
    bf16* p   = (bf16*)d_ws;
    bf16* Xb  = p;  p += NX;
    bf16* Wqt = p;  p += (size_t)(3 * CC) * CC;
    bf16* Wot = p;  p += (size_t)CC * CC;
    bf16* Qb  = p;  p += NX;
    bf16* Kb  = p;  p += NX;
    bf16* Vtb = p;  p += NX;
    bf16* Yb  = Xb;                              // alias: Xb dead after GEMM1

    // fused conversions (one launch)
    k_prep<<<2048, 256, 0, stream>>>(x, wqkv, wout, Xb, Wqt, Wot);

    // QKV projection with V^T scatter
    k_gemm_bt<1><<<(BB * TT / 128) * (3 * CC / 128), 256, 0, stream>>>(
        Xb, Wqt, BB * TT, 3 * CC, CC, nullptr, Qb, Kb, Vtb);

    // causal flash attention -> Yb (512 blocks x 8 waves)
    k_attn<<<512, 512, 0, stream>>>(Qb, Kb, Vtb, Yb);

    // output projection -> fp32 out
    k_gemm_bt<0><<<(BB * TT / 128) * (CC / 128), 256, 0, stream>>>(
        Yb, Wot, BB * TT, CC, CC, out, nullptr, nullptr, nullptr);
}

// Round 20
// 123.089 us; speedup vs baseline: 1.0024x; 1.0024x over previous
//
#include <hip/hip_runtime.h>
#include <hip/hip_bf16.h>

typedef __bf16 bf16;
typedef __bf16 bf16x4 __attribute__((ext_vector_type(4)));
typedef __bf16 bf16x8 __attribute__((ext_vector_type(8)));
typedef float  f32x4  __attribute__((ext_vector_type(4)));

// Problem constants: B=16, T=1024, C=512, H=8, Dh=64
#define BB 16
#define TT 1024
#define CC 512
#define HH 8
#define DH 64

// 0.125 (1/sqrt(Dh)) * log2(e): folded into Q so softmax uses exp2 directly.
#define QSCALE 0.18033688011112042f
#define RESCALE_THR 10.0f

__device__ __forceinline__ void gload16(const void* gsrc, void* ldst) {
    __builtin_amdgcn_global_load_lds(
        (const __attribute__((address_space(1))) void*)gsrc,
        (__attribute__((address_space(3))) void*)ldst, 16, 0, 0);
}

__device__ __forceinline__ f32x4 mfma16(bf16x8 a, bf16x8 b, f32x4 c) {
    return __builtin_amdgcn_mfma_f32_16x16x32_bf16(a, b, c, 0, 0, 0);
}

// ---------------- fused prep: x->bf16, Wqkv^T, Wout^T in one launch ----------------
__global__ __launch_bounds__(256)
void k_prep(const float* __restrict__ x, const float* __restrict__ wqkv,
            const float* __restrict__ wout,
            bf16* __restrict__ xb, bf16* __restrict__ wqt, bf16* __restrict__ wot)
{
    const int stride = gridDim.x * blockDim.x;
    const int i0 = blockIdx.x * blockDim.x + threadIdx.x;
    const int NX4 = BB * TT * CC / 4;
    for (int i = i0; i < NX4; i += stride) {
        float4 v = *(const float4*)(x + (size_t)i * 4);
        bf16x4 o = { (bf16)v.x, (bf16)v.y, (bf16)v.z, (bf16)v.w };
        *(bf16x4*)(xb + (size_t)i * 4) = o;
    }
    const int NQ = CC * 3 * CC;
    for (int i = i0; i < NQ; i += stride) {
        int k = i / (3 * CC), n = i - k * (3 * CC);
        wqt[(size_t)n * CC + k] = (bf16)wqkv[i];
    }
    const int NO = CC * CC;
    for (int i = i0; i < NO; i += stride) {
        int k = i / CC, n = i - k * CC;
        wot[(size_t)n * CC + k] = (bf16)wout[i];
    }
}

// ---------------- flash attention v9: 8 waves x 16 rows ----------------
// R20: byte-exact R15/R16 attn source (the build where it ran ~37us), but
// defined BEFORE k_gemm_bt — re-rolls the module regalloc context that R17's
// GEMM rewrite perturbed (rule #19). No launch_bounds min-occ, no sched_barrier
// (both measured null).
__global__ __launch_bounds__(512)
void k_attn(const bf16* __restrict__ qg, const bf16* __restrict__ kg,
            const bf16* __restrict__ vtg, bf16* __restrict__ yb)
{
    __shared__ __align__(16) bf16 sK[2][32 * 72];   // [k-row][dh], row stride 72
    __shared__ __align__(16) bf16 sV[2][64 * 40];   // [d][k],     row stride 40
    __shared__ __align__(16) bf16 sP[8][16 * 40];   // per-wave P tile (16 rows)
    const int tid = threadIdx.x, w = tid >> 6, lane = tid & 63;
    const int l15 = lane & 15, l4 = lane >> 4;

    const int bid = blockIdx.x;          // 0..511
    const int xcd = bid & 7;
    const int j   = bid >> 3;            // 0..63
    const int bh  = xcd * 16 + (j >> 2); // 0..127
    const int qp  = j & 3;               // pair id 0..3

    const bf16* Q  = qg  + (size_t)bh * TT * DH;
    const bf16* Kp = kg  + (size_t)bh * TT * DH;
    const bf16* Vt = vtg + (size_t)bh * DH * TT;
    const int b = bh >> 3, h = bh & 7;

    const bool kstage = (tid < 256);
    const int ks_row = tid >> 3;                  // 0..31 (valid when kstage)
    const int ks_col = (tid & 7) * 8;             // 0..56
    const int t2 = tid & 255;
    const int vs_row = t2 >> 2;                   // 0..63 (d)
    const int vs_col = (t2 & 3) * 8;              // 0..24

    bf16* myP = &sP[w][0];
    const f32x4 zero = {0.f, 0.f, 0.f, 0.f};

    for (int up = 0; up < 2; ++up) {
        const int qblk = up ? (7 - qp) : qp;   // q-block 0..7 (128 rows)
        const int qb   = qblk * 128 + w * 16;  // this wave's 16 q-rows [qb, qb+16)
        const int nt   = (qblk + 1) * 4;       // causal KV tiles of 32

        bf16x8 qf[2];
#pragma unroll
        for (int kk = 0; kk < 2; ++kk)
            qf[kk] = *(const bf16x8*)(Q + (size_t)(qb + l15) * DH + kk * 32 + l4 * 8);

        f32x4 y[4];
        float m_ = -1e30f, lp_ = 0.f;
#pragma unroll
        for (int dj = 0; dj < 4; ++dj) y[dj] = zero;

        if (kstage) {
            uint4 k0 = *(const uint4*)(Kp + (size_t)ks_row * DH + ks_col);
            *(uint4*)(&sK[0][ks_row * 72 + ks_col]) = k0;
        } else {
            uint4 v0 = *(const uint4*)(Vt + (size_t)vs_row * TT + vs_col);
            *(uint4*)(&sV[0][vs_row * 40 + vs_col]) = v0;
        }
        __syncthreads();

        for (int t = 0; t < nt; ++t) {
            const int t0 = t * 32;
            const int cur = t & 1, nxt = cur ^ 1;
            const bool more = (t + 1 < nt);
            uint4 sreg;
            if (more) {   // T14: issue next tile's global load early
                sreg = kstage
                    ? *(const uint4*)(Kp + (size_t)(t0 + 32 + ks_row) * DH + ks_col)
                    : *(const uint4*)(Vt + (size_t)vs_row * TT + t0 + 32 + vs_col);
            }

            if (t0 < qb + 16) {   // wave-uniform causal skip
                bf16x8 kf[2][2];
#pragma unroll
                for (int nj = 0; nj < 2; ++nj) {
                    const int row = nj * 16 + l15;
#pragma unroll
                    for (int kk = 0; kk < 2; ++kk)
                        kf[nj][kk] = *(const bf16x8*)(&sK[cur][row * 72 + ((kk << 2) | l4) * 8]);
                }
                f32x4 s[2];
#pragma unroll
                for (int nj = 0; nj < 2; ++nj) {
                    f32x4 a = mfma16(kf[nj][0], qf[0], zero);
                    s[nj] = mfma16(kf[nj][1], qf[1], a);
                }
                if (t0 + 32 > qb) {   // straddling tile: absolute-coord mask
#pragma unroll
                    for (int nj = 0; nj < 2; ++nj)
#pragma unroll
                        for (int rg = 0; rg < 4; ++rg)
                            if (t0 + nj * 16 + l4 * 4 + rg > qb + l15)
                                s[nj][rg] = -1e30f;
                }
                float mx = fmaxf(fmaxf(fmaxf(s[0][0], s[0][1]), fmaxf(s[0][2], s[0][3])),
                                 fmaxf(fmaxf(s[1][0], s[1][1]), fmaxf(s[1][2], s[1][3])));
                mx = fmaxf(mx, __shfl_xor(mx, 16));
                mx = fmaxf(mx, __shfl_xor(mx, 32));
                if (__any(mx > m_ + RESCALE_THR)) {   // T13 defer-rescale
                    float mnew = fmaxf(m_, mx);
                    float corr = exp2f(m_ - mnew);
                    lp_ *= corr;
                    float cr[4];
#pragma unroll
                    for (int rg = 0; rg < 4; ++rg)
                        cr[rg] = __shfl(corr, ((lane >> 4) << 2) | rg);
#pragma unroll
                    for (int dj = 0; dj < 4; ++dj)
#pragma unroll
                        for (int rg = 0; rg < 4; ++rg) y[dj][rg] *= cr[rg];
                    m_ = mnew;
                }
                bf16x4 pk0, pk1;
#pragma unroll
                for (int rg = 0; rg < 4; ++rg) {
                    float p0 = exp2f(s[0][rg] - m_);
                    float p1 = exp2f(s[1][rg] - m_);
                    lp_ += p0 + p1;
                    pk0[rg] = (bf16)p0;
                    pk1[rg] = (bf16)p1;
                }
                *(bf16x4*)(myP + l15 * 40 + l4 * 4)      = pk0;
                *(bf16x4*)(myP + l15 * 40 + 16 + l4 * 4) = pk1;

                bf16x8 pa = *(const bf16x8*)(myP + l15 * 40 + l4 * 8);
                bf16x8 vf[4];
#pragma unroll
                for (int dj = 0; dj < 4; ++dj)
                    vf[dj] = *(const bf16x8*)(&sV[cur][(dj * 16 + l15) * 40 + l4 * 8]);
#pragma unroll
                for (int dj = 0; dj < 4; ++dj)
                    y[dj] = mfma16(pa, vf[dj], y[dj]);
            }

            if (more) {   // T14: write-late into the other buffer (split)
                if (kstage) *(uint4*)(&sK[nxt][ks_row * 72 + ks_col]) = sreg;
                else        *(uint4*)(&sV[nxt][vs_row * 40 + vs_col]) = sreg;
            }
            __syncthreads();
        }

        // epilogue: row denominator, redistribute to y-row layout, store
        lp_ += __shfl_xor(lp_, 16);
        lp_ += __shfl_xor(lp_, 32);
#pragma unroll
        for (int rg = 0; rg < 4; ++rg) {
            float inv = 1.0f / __shfl(lp_, ((lane >> 4) << 2) | rg);
            int rr = qb + l4 * 4 + rg;
#pragma unroll
            for (int dj = 0; dj < 4; ++dj) {
                int cc = h * DH + dj * 16 + l15;
                yb[((size_t)b * TT + rr) * CC + cc] = (bf16)(y[dj][rg] * inv);
            }
        }
        __syncthreads();   // protect sK/sV reuse across up iterations
    }
}

// ---------------- GEMM: C[M,N] = A[M,K] * Bt[N,K]^T ----------------
// (byte-identical to R17) Swapped MFMA operands -> rg spans 4 consecutive
// columns -> vectorized epilogue (f32x4 / bf16x4 stores). BK=64, linear
// global_load_lds staging, XCD-aware swizzle.
template<int MODE>
__global__ __launch_bounds__(256)
void k_gemm_bt(const bf16* __restrict__ A, const bf16* __restrict__ Bt,
               int M, int N, int K,
               float* __restrict__ outF,
               bf16* __restrict__ qb, bf16* __restrict__ kb, bf16* __restrict__ vtb)
{
    __shared__ bf16 sA[2 * 128 * 32];   // [kk][row][32]
    __shared__ bf16 sB[2 * 128 * 32];
    const int tid  = threadIdx.x;
    const int wid  = tid >> 6;
    const int lane = tid & 63;
    const int l15  = lane & 15, l4 = lane >> 4;

    const int cpx = gridDim.x >> 3;
    const int bid = (blockIdx.x & 7) * cpx + (blockIdx.x >> 3);

    const int nNt = N >> 7;
    const int mt  = bid / nNt;
    const int nt  = bid - mt * nNt;
    const int m0  = mt << 7, n0 = nt << 7;
    const int wr  = (wid >> 1) * 64, wc = (wid & 1) * 64;

    f32x4 zero = {0.f, 0.f, 0.f, 0.f};
    f32x4 acc[4][4];
#pragma unroll
    for (int i = 0; i < 4; ++i)
#pragma unroll
        for (int j = 0; j < 4; ++j) acc[i][j] = zero;

    int srow[4], scol[4], soff[4];
#pragma unroll
    for (int c = 0; c < 4; ++c) {
        const int cc = wid * 4 + c;                  // 0..15
        srow[c] = (cc & 7) * 16 + (lane >> 2);       // tile row 0..127
        scol[c] = (cc >> 3) * 32 + (lane & 3) * 8;   // k offset within 64
        soff[c] = cc * 512;                          // LDS elem base (wave-uniform)
    }

    for (int k0 = 0; k0 < K; k0 += 64) {
#pragma unroll
        for (int c = 0; c < 4; ++c)
            gload16(A  + (size_t)(m0 + srow[c]) * K + k0 + scol[c], sA + soff[c]);
#pragma unroll
        for (int c = 0; c < 4; ++c)
            gload16(Bt + (size_t)(n0 + srow[c]) * K + k0 + scol[c], sB + soff[c]);
        __syncthreads();
        bf16x8 af[4][2], bfr[4][2];
#pragma unroll
        for (int kk = 0; kk < 2; ++kk) {
#pragma unroll
            for (int i = 0; i < 4; ++i)
                af[i][kk] = *(const bf16x8*)(sA + kk * 4096 + (wr + i * 16 + l15) * 32 + l4 * 8);
#pragma unroll
            for (int j = 0; j < 4; ++j)
                bfr[j][kk] = *(const bf16x8*)(sB + kk * 4096 + (wc + j * 16 + l15) * 32 + l4 * 8);
        }
#pragma unroll
        for (int kk = 0; kk < 2; ++kk)
#pragma unroll
            for (int i = 0; i < 4; ++i)
#pragma unroll
                for (int j = 0; j < 4; ++j)
                    acc[i][j] = mfma16(bfr[j][kk], af[i][kk], acc[i][j]);   // swapped
        __syncthreads();
    }

    // vectorized epilogue: rm per (i); cn0..cn0+3 contiguous per (i,j)
#pragma unroll
    for (int i = 0; i < 4; ++i) {
        const int rm = m0 + wr + i * 16 + l15;
#pragma unroll
        for (int j = 0; j < 4; ++j) {
            const int cn0 = n0 + wc + j * 16 + l4 * 4;
            if (MODE == 0) {
                *(f32x4*)(&outF[(size_t)rm * N + cn0]) = acc[i][j];
            } else {
                int b = rm >> 10, t = rm & 1023;
                int s = cn0 >> 9, h = (cn0 >> 6) & 7, d0 = cn0 & 63;
                size_t bh = (size_t)(b * HH + h);
                if (s == 0) {
                    bf16x4 o = { (bf16)(acc[i][j][0] * QSCALE), (bf16)(acc[i][j][1] * QSCALE),
                                 (bf16)(acc[i][j][2] * QSCALE), (bf16)(acc[i][j][3] * QSCALE) };
                    *(bf16x4*)(qb + (bh * TT + t) * DH + d0) = o;
                } else if (s == 1) {
                    bf16x4 o = { (bf16)acc[i][j][0], (bf16)acc[i][j][1],
                                 (bf16)acc[i][j][2], (bf16)acc[i][j][3] };
                    *(bf16x4*)(kb + (bh * TT + t) * DH + d0) = o;
                } else {
#pragma unroll
                    for (int rg = 0; rg < 4; ++rg)
                        vtb[(bh * DH + d0 + rg) * TT + t] = (bf16)acc[i][j][rg];
                }
            }
        }
    }
}

// ---------------- launch ----------------
extern "C" void kernel_launch(void* const* d_in, const int* in_sizes, int n_in,
                              void* d_out, int out_size, void* d_ws, size_t ws_size,
                              hipStream_t stream)
{
    const float* x    = (const float*)d_in[0];   // [16,1024,512]
    const float* wqkv = (const float*)d_in[1];   // [512,1536]
    const float* wout = (const float*)d_in[2];   // [512,512]
    float* out = (float*)d_out;                  // [16,1024,512] fp32

    const size_t NX = (size_t)BB * TT * CC;
    bf16* p   = (bf16*)d_ws;
    bf16* Xb  = p;  p += NX;
    bf16* Wqt = p;  p += (size_t)(3 * CC) * CC;
    bf16* Wot = p;  p += (size_t)CC * CC;
    bf16* Qb  = p;  p += NX;
    bf16* Kb  = p;  p += NX;
    bf16* Vtb = p;  p += NX;
    bf16* Yb  = Xb;                              // alias: Xb dead after GEMM1

    // fused conversions (one launch)
    k_prep<<<2048, 256, 0, stream>>>(x, wqkv, wout, Xb, Wqt, Wot);

    // QKV projection with V^T scatter
    k_gemm_bt<1><<<(BB * TT / 128) * (3 * CC / 128), 256, 0, stream>>>(
        Xb, Wqt, BB * TT, 3 * CC, CC, nullptr, Qb, Kb, Vtb);

    // causal flash attention -> Yb (512 blocks x 8 waves)
    k_attn<<<512, 512, 0, stream>>>(Qb, Kb, Vtb, Yb);

    // output projection -> fp32 out
    k_gemm_bt<0><<<(BB * TT / 128) * (CC / 128), 256, 0, stream>>>(
        Yb, Wot, BB * TT, CC, CC, out, nullptr, nullptr, nullptr);
}